// Round 4
// baseline (143.136 us; speedup 1.0000x reference)
//
#include <hip/hip_runtime.h>
#include <math.h>

#define MA 64
#define ME 256
#define DM 256
#define DQK 32
#define ENVSTRIDE (MA * ME)            // 16384 floats per env (logits region / staging region)
#define MASKVAL -998244352.0f          // bf16-rounded -1e9 (matches reference)
#define QK_SCALE 0.17677669529663687f  // 1/sqrt(32)

__device__ __forceinline__ int lb(const int* __restrict__ a, int n, int v){
  int lo = 0, hi = n;
  while (lo < hi){ int mid = (lo + hi) >> 1; if (a[mid] < v) lo = mid + 1; else hi = mid; }
  return lo;
}
__device__ __forceinline__ float4 f4fma(float s, float4 a, float4 acc){
  acc.x = fmaf(s, a.x, acc.x); acc.y = fmaf(s, a.y, acc.y);
  acc.z = fmaf(s, a.z, acc.z); acc.w = fmaf(s, a.w, acc.w); return acc;
}
__device__ __forceinline__ float dot4(float4 a, float4 b){
  return a.x * b.x + a.y * b.y + a.z * b.z + a.w * b.w;
}

// ================= K2: projection (keys then queries), 8 lanes per row =================
// job < E: key -> stage[env*16384 + pos*32]; job-E < A: query -> stage[env*16384 + 8192 + pos*32]
__global__ __launch_bounds__(256, 6)
void proj_kernel(const float* __restrict__ x,
                 const float* __restrict__ Wq, const float* __restrict__ bq,
                 const float* __restrict__ Wk, const float* __restrict__ bk,
                 const int* __restrict__ actors, const int* __restrict__ qindices,
                 const int* __restrict__ actees, const int* __restrict__ kindices,
                 int A, int E, float* __restrict__ stage)
{
  const int t   = threadIdx.x;
  const int job = blockIdx.x * 32 + (t >> 3);
  const int cg  = t & 7;
  if (job >= E + A) return;

  const float *W, *bias, *xr;
  float* dst;
  if (job < E) {
    int idx = kindices[job];
    int env = idx >> 8, pos = idx & (ME - 1);
    W = Wk; bias = bk;
    xr  = x + (size_t)actees[job] * DM;
    dst = stage + (size_t)env * ENVSTRIDE + pos * DQK;
  } else {
    int jq  = job - E;
    int idx = qindices[jq];
    int env = idx >> 6, pos = idx & (MA - 1);
    W = Wq; bias = bq;
    xr  = x + (size_t)actors[jq] * DM;
    dst = stage + (size_t)env * ENVSTRIDE + ME * DQK + pos * DQK;
  }

  const float* wp = W + cg * 4;
  float4 acc = make_float4(0.f, 0.f, 0.f, 0.f);
  #pragma unroll 2
  for (int m = 0; m < DM; m += 4) {
    float4 xv = *(const float4*)(xr + m);
    float4 w0 = *(const float4*)(wp + (m + 0) * DQK);
    float4 w1 = *(const float4*)(wp + (m + 1) * DQK);
    float4 w2 = *(const float4*)(wp + (m + 2) * DQK);
    float4 w3 = *(const float4*)(wp + (m + 3) * DQK);
    acc = f4fma(xv.x, w0, acc);
    acc = f4fma(xv.y, w1, acc);
    acc = f4fma(xv.z, w2, acc);
    acc = f4fma(xv.w, w3, acc);
  }
  float4 bv = *(const float4*)(bias + cg * 4);
  acc.x += bv.x; acc.y += bv.y; acc.z += bv.z; acc.w += bv.w;
  *(float4*)(dst + cg * 4) = acc;
}

// ================= K3: logits + online softmax, one block per env =================
__global__ __launch_bounds__(256, 3)
void logits_kernel(const int* __restrict__ qindices, const int* __restrict__ kindices,
                   const int* __restrict__ prev_actions, const float* __restrict__ stage,
                   int A, int E, float* __restrict__ out)
{
  __shared__ float kb[ME][DQK];      // XOR-swizzled float4 slots: conflict-free reads
  __shared__ int srange[4];

  const int t = threadIdx.x, b = blockIdx.x;

  if (t < 4) {
    const int* arr = (t < 2) ? qindices : kindices;
    const int  n   = (t < 2) ? A : E;
    const int  v   = (t < 2) ? (b + (t & 1)) * MA : (b - 2 + (t & 1) + 2 - t + t) * 0; // placeholder
    // compute properly below
    int vv = (t == 0) ? b * MA : (t == 1) ? (b + 1) * MA : (t == 2) ? b * ME : (b + 1) * ME;
    srange[t] = lb(arr, n, vv);
  }
  __syncthreads();
  const int qstart = srange[0], qlen = srange[1] - srange[0];
  const int klen   = srange[3] - srange[2];

  const float* envst = stage + (size_t)b * ENVSTRIDE;

  // stage keys into LDS (coalesced global float4, XOR-swizzled LDS slots)
  #pragma unroll
  for (int i = 0; i < 8; ++i) {
    int f = t + i * 256;             // float4 index: row = f>>3, slot c = f&7
    int row = f >> 3, c = f & 7;
    if (row < klen)
      *(float4*)&kb[row][((c ^ (row & 7)) << 2)] = *(const float4*)(envst + f * 4);
  }

  // queries to registers (uniform within 8-lane group; L2-hot broadcast loads)
  const int j = t & 7, g = t >> 3;
  const int r0 = 2 * g, r1 = r0 + 1;
  const bool v0 = (r0 < qlen), v1 = (r1 < qlen);
  float4 qv0[8], qv1[8];
  {
    const float* qbase = envst + ME * DQK;
    const int r0s = v0 ? r0 : 0, r1s = v1 ? r1 : r0s;
    #pragma unroll
    for (int c = 0; c < 8; ++c) qv0[c] = *(const float4*)(qbase + r0s * DQK + c * 4);
    #pragma unroll
    for (int c = 0; c < 8; ++c) qv1[c] = *(const float4*)(qbase + r1s * DQK + c * 4);
  }
  int pa0 = v0 ? (prev_actions[qstart + r0] & (ME - 1)) : -1;
  int pa1 = v1 ? (prev_actions[qstart + r1] & (ME - 1)) : -1;

  __syncthreads();   // staging complete; safe to overwrite env region with logits

  float* out_lg = out + (size_t)3 * A + (size_t)b * ENVSTRIDE;

  if (!v0) {         // both rows padded: plain MASKVAL fill (coalesced scalar runs)
    #pragma unroll
    for (int s = 0; s < 32; ++s) {
      out_lg[r0 * ME + j + 8 * s] = MASKVAL;
      out_lg[r1 * ME + j + 8 * s] = MASKVAL;
    }
    return;
  }

  float m0 = MASKVAL, e0 = 0.f, t0 = 0.f, spa0 = MASKVAL;
  float m1 = MASKVAL, e1 = 0.f, t1 = 0.f, spa1 = MASKVAL;

  for (int s = 0; s < 32; ++s) {
    const int k = j + 8 * s;
    const bool kval = (k < klen);
    float d0 = MASKVAL, d1 = MASKVAL;
    if (kval) {
      float a0 = 0.f, a1 = 0.f;
      #pragma unroll
      for (int c = 0; c < 8; ++c) {
        float4 kv = *(const float4*)&kb[k][((c ^ (k & 7)) << 2)];
        a0 += dot4(qv0[c], kv);
        a1 += dot4(qv1[c], kv);
      }
      d0 = a0 * QK_SCALE;
      d1 = v1 ? a1 * QK_SCALE : MASKVAL;
    }
    out_lg[r0 * ME + k] = d0;
    out_lg[r1 * ME + k] = d1;
    if (k == pa0) spa0 = d0;
    if (k == pa1) spa1 = d1;

    // online softmax update, row 0
    {
      float nm = fmaxf(m0, d0);
      float sc = expf(m0 - nm);
      float ed = kval ? expf(d0 - nm) : 0.f;
      t0 = (t0 + e0 * (m0 - nm)) * sc + ed * (d0 - nm);
      e0 = e0 * sc + ed;
      m0 = nm;
    }
    if (v1) {
      float nm = fmaxf(m1, d1);
      float sc = expf(m1 - nm);
      float ed = kval ? expf(d1 - nm) : 0.f;
      t1 = (t1 + e1 * (m1 - nm)) * sc + ed * (d1 - nm);
      e1 = e1 * sc + ed;
      m1 = nm;
    }
  }

  // merge 8 lanes (butterfly)
  #pragma unroll
  for (int off = 1; off < 8; off <<= 1) {
    float om = __shfl_xor(m0, off), oe = __shfl_xor(e0, off), ot = __shfl_xor(t0, off);
    float M  = fmaxf(m0, om);
    float sa = expf(m0 - M), sb = expf(om - M);
    t0 = (t0 + e0 * (m0 - M)) * sa + (ot + oe * (om - M)) * sb;
    e0 = e0 * sa + oe * sb;
    m0 = M;
    spa0 = fmaxf(spa0, __shfl_xor(spa0, off));

    float om1 = __shfl_xor(m1, off), oe1 = __shfl_xor(e1, off), ot1 = __shfl_xor(t1, off);
    float M1  = fmaxf(m1, om1);
    float sa1 = expf(m1 - M1), sb1 = expf(om1 - M1);
    t1 = (t1 + e1 * (m1 - M1)) * sa1 + (ot1 + oe1 * (om1 - M1)) * sb1;
    e1 = e1 * sa1 + oe1 * sb1;
    m1 = M1;
    spa1 = fmaxf(spa1, __shfl_xor(spa1, off));
  }

  if (j == 0) {
    float lS0 = logf(fmaxf(e0, 1e-30f));
    out[qstart + r0]         = (float)pa0;
    out[A + qstart + r0]     = spa0 - m0 - lS0;
    out[2 * A + qstart + r0] = lS0 - t0 / e0;
    if (v1) {
      float lS1 = logf(fmaxf(e1, 1e-30f));
      out[qstart + r1]         = (float)pa1;
      out[A + qstart + r1]     = spa1 - m1 - lS1;
      out[2 * A + qstart + r1] = lS1 - t1 / e1;
    }
  }
}

extern "C" void kernel_launch(void* const* d_in, const int* in_sizes, int n_in,
                              void* d_out, int out_size, void* d_ws, size_t ws_size,
                              hipStream_t stream) {
  const float* x  = (const float*)d_in[0];
  const float* Wq = (const float*)d_in[1];
  const float* bq = (const float*)d_in[2];
  const float* Wk = (const float*)d_in[3];
  const float* bk = (const float*)d_in[4];
  const int* actors       = (const int*)d_in[5];
  const int* qindices     = (const int*)d_in[6];
  const int* actees       = (const int*)d_in[7];
  const int* kindices     = (const int*)d_in[8];
  const int* prev_actions = (const int*)d_in[9];

  const int A = in_sizes[5];
  const int E = in_sizes[7];
  const int B = (out_size - 3 * A) / ENVSTRIDE;
  if (B <= 0) return;

  float* out = (float*)d_out;
  // 16B-aligned staging inside the logits region (each env uses 10243 < 16384 floats)
  float* stg = out + (((size_t)3 * A + 3) & ~(size_t)3);

  const int jobs = E + A;
  proj_kernel<<<dim3((jobs + 31) / 32), dim3(256), 0, stream>>>(
      x, Wq, bq, Wk, bk, actors, qindices, actees, kindices, A, E, stg);
  logits_kernel<<<dim3(B), dim3(256), 0, stream>>>(
      qindices, kindices, prev_actions, stg, A, E, out);
}

// Round 5
// 134.874 us; speedup vs baseline: 1.0613x; 1.0613x over previous
//
#include <hip/hip_runtime.h>
#include <math.h>

#define MA 64
#define ME 256
#define DM 256
#define DQK 32
#define ENVSTRIDE (MA * ME)            // 16384 floats per env
#define MASKVAL -998244352.0f          // bf16-rounded -1e9 (matches reference)
#define QK_SCALE 0.17677669529663687f  // 1/sqrt(32)
#define ROWS 32                        // rows per proj block

__device__ __forceinline__ int lb(const int* __restrict__ a, int n, int v){
  int lo = 0, hi = n;
  while (lo < hi){ int mid = (lo + hi) >> 1; if (a[mid] < v) lo = mid + 1; else hi = mid; }
  return lo;
}
__device__ __forceinline__ float4 f4fma(float s, float4 a, float4 acc){
  acc.x = fmaf(s, a.x, acc.x); acc.y = fmaf(s, a.y, acc.y);
  acc.z = fmaf(s, a.z, acc.z); acc.w = fmaf(s, a.w, acc.w); return acc;
}
__device__ __forceinline__ float dot4(float4 a, float4 b){
  return a.x * b.x + a.y * b.y + a.z * b.z + a.w * b.w;
}

// ================= K1: projection. 32 rows/block; x rows fetched as 1KB coalesced bursts =================
__global__ __launch_bounds__(256)
void proj_kernel(const float* __restrict__ x,
                 const float* __restrict__ Wq, const float* __restrict__ bq,
                 const float* __restrict__ Wk, const float* __restrict__ bk,
                 const int* __restrict__ actors, const int* __restrict__ qindices,
                 const int* __restrict__ actees, const int* __restrict__ kindices,
                 int A, int E, float* __restrict__ stage)
{
  __shared__ float xs[ROWS][DM + 4];   // stride 260 floats: conflict-free octet reads

  const int t = threadIdx.x;
  const int w = t >> 6, lane = t & 63;
  const int jobs = E + A;
  const int job0 = blockIdx.x * ROWS;

  // ---- stage: wave w fetches rows 8w..8w+7, each as one 1KB coalesced burst ----
  #pragma unroll
  for (int i = 0; i < 8; ++i) {
    const int r = w * 8 + i;
    const int job = job0 + r;
    if (job < jobs) {
      const int src = (job < E) ? actees[job] : actors[job - E];   // wave-uniform -> s_load
      const float4 xv = *(const float4*)(x + (size_t)src * DM + lane * 4);
      *(float4*)&xs[r][lane * 4] = xv;
    }
  }
  __syncthreads();

  // ---- compute: 8-lane group per row, 4 cols per lane ----
  const int g = lane >> 3, cg = lane & 7;
  const int r = w * 8 + g;
  const int job = job0 + r;
  if (job >= jobs) return;

  const bool iskey = (job < E);
  const float* W    = iskey ? Wk : Wq;
  const float* bias = iskey ? bk : bq;
  const float* wp = W + cg * 4;

  float4 acc = make_float4(0.f, 0.f, 0.f, 0.f);
  #pragma unroll 4
  for (int m = 0; m < DM; m += 4) {
    float4 xv = *(const float4*)&xs[r][m];
    float4 w0 = *(const float4*)(wp + (m + 0) * DQK);
    float4 w1 = *(const float4*)(wp + (m + 1) * DQK);
    float4 w2 = *(const float4*)(wp + (m + 2) * DQK);
    float4 w3 = *(const float4*)(wp + (m + 3) * DQK);
    acc = f4fma(xv.x, w0, acc);
    acc = f4fma(xv.y, w1, acc);
    acc = f4fma(xv.z, w2, acc);
    acc = f4fma(xv.w, w3, acc);
  }
  float4 bv = *(const float4*)(bias + cg * 4);
  acc.x += bv.x; acc.y += bv.y; acc.z += bv.z; acc.w += bv.w;

  size_t dstoff;
  if (iskey) {
    int idx = kindices[job];
    dstoff = (size_t)(idx >> 8) * ENVSTRIDE + (idx & (ME - 1)) * DQK;
  } else {
    int idx = qindices[job - E];
    dstoff = (size_t)(idx >> 6) * ENVSTRIDE + ME * DQK + (idx & (MA - 1)) * DQK;
  }
  *(float4*)(stage + dstoff + cg * 4) = acc;
}

// ================= K2: logits + online softmax, one block per env =================
__global__ __launch_bounds__(256, 3)
void logits_kernel(const int* __restrict__ qindices, const int* __restrict__ kindices,
                   const int* __restrict__ prev_actions, const float* __restrict__ stage,
                   int A, int E, float* __restrict__ out)
{
  __shared__ float kb[ME][DQK];      // XOR-swizzled float4 slots: conflict-free reads
  __shared__ int srange[4];

  const int t = threadIdx.x, b = blockIdx.x;

  if (t < 4) {
    const int* arr = (t < 2) ? qindices : kindices;
    const int  n   = (t < 2) ? A : E;
    const int  vv  = (t == 0) ? b * MA : (t == 1) ? (b + 1) * MA
                   : (t == 2) ? b * ME : (b + 1) * ME;
    srange[t] = lb(arr, n, vv);
  }
  __syncthreads();
  const int qstart = srange[0], qlen = srange[1] - srange[0];
  const int klen   = srange[3] - srange[2];

  const float* envst = stage + (size_t)b * ENVSTRIDE;

  // stage keys into LDS (coalesced global float4, XOR-swizzled LDS slots)
  #pragma unroll
  for (int i = 0; i < 8; ++i) {
    int f = t + i * 256;             // float4 index: row = f>>3, slot c = f&7
    int row = f >> 3, c = f & 7;
    if (row < klen)
      *(float4*)&kb[row][((c ^ (row & 7)) << 2)] = *(const float4*)(envst + f * 4);
  }

  // queries to registers (uniform within 8-lane group; L2-hot broadcast loads)
  const int j = t & 7, g = t >> 3;
  const int r0 = 2 * g, r1 = r0 + 1;
  const bool v0 = (r0 < qlen), v1 = (r1 < qlen);
  float4 qv0[8], qv1[8];
  {
    const float* qbase = envst + ME * DQK;
    const int r0s = v0 ? r0 : 0, r1s = v1 ? r1 : r0s;
    #pragma unroll
    for (int c = 0; c < 8; ++c) qv0[c] = *(const float4*)(qbase + r0s * DQK + c * 4);
    #pragma unroll
    for (int c = 0; c < 8; ++c) qv1[c] = *(const float4*)(qbase + r1s * DQK + c * 4);
  }
  int pa0 = v0 ? (prev_actions[qstart + r0] & (ME - 1)) : -1;
  int pa1 = v1 ? (prev_actions[qstart + r1] & (ME - 1)) : -1;

  __syncthreads();   // staging complete; safe to overwrite env region with logits

  float* out_lg = out + (size_t)3 * A + (size_t)b * ENVSTRIDE;

  if (!v0) {         // both rows padded: plain MASKVAL fill
    #pragma unroll
    for (int s = 0; s < 32; ++s) {
      out_lg[r0 * ME + j + 8 * s] = MASKVAL;
      out_lg[r1 * ME + j + 8 * s] = MASKVAL;
    }
    return;
  }

  float m0 = MASKVAL, e0 = 0.f, t0 = 0.f, spa0 = MASKVAL;
  float m1 = MASKVAL, e1 = 0.f, t1 = 0.f, spa1 = MASKVAL;

  for (int s = 0; s < 32; ++s) {
    const int k = j + 8 * s;
    const bool kval = (k < klen);
    float d0 = MASKVAL, d1 = MASKVAL;
    if (kval) {
      float a0 = 0.f, a1 = 0.f;
      #pragma unroll
      for (int c = 0; c < 8; ++c) {
        float4 kv = *(const float4*)&kb[k][((c ^ (k & 7)) << 2)];
        a0 += dot4(qv0[c], kv);
        a1 += dot4(qv1[c], kv);
      }
      d0 = a0 * QK_SCALE;
      d1 = v1 ? a1 * QK_SCALE : MASKVAL;
    }
    out_lg[r0 * ME + k] = d0;
    out_lg[r1 * ME + k] = d1;
    if (k == pa0) spa0 = d0;
    if (k == pa1) spa1 = d1;

    {
      float nm = fmaxf(m0, d0);
      float sc = expf(m0 - nm);
      float ed = kval ? expf(d0 - nm) : 0.f;
      t0 = (t0 + e0 * (m0 - nm)) * sc + ed * (d0 - nm);
      e0 = e0 * sc + ed;
      m0 = nm;
    }
    if (v1) {
      float nm = fmaxf(m1, d1);
      float sc = expf(m1 - nm);
      float ed = kval ? expf(d1 - nm) : 0.f;
      t1 = (t1 + e1 * (m1 - nm)) * sc + ed * (d1 - nm);
      e1 = e1 * sc + ed;
      m1 = nm;
    }
  }

  // merge 8 lanes (butterfly)
  #pragma unroll
  for (int off = 1; off < 8; off <<= 1) {
    float om = __shfl_xor(m0, off), oe = __shfl_xor(e0, off), ot = __shfl_xor(t0, off);
    float M  = fmaxf(m0, om);
    float sa = expf(m0 - M), sb = expf(om - M);
    t0 = (t0 + e0 * (m0 - M)) * sa + (ot + oe * (om - M)) * sb;
    e0 = e0 * sa + oe * sb;
    m0 = M;
    spa0 = fmaxf(spa0, __shfl_xor(spa0, off));

    float om1 = __shfl_xor(m1, off), oe1 = __shfl_xor(e1, off), ot1 = __shfl_xor(t1, off);
    float M1  = fmaxf(m1, om1);
    float sa1 = expf(m1 - M1), sb1 = expf(om1 - M1);
    t1 = (t1 + e1 * (m1 - M1)) * sa1 + (ot1 + oe1 * (om1 - M1)) * sb1;
    e1 = e1 * sa1 + oe1 * sb1;
    m1 = M1;
    spa1 = fmaxf(spa1, __shfl_xor(spa1, off));
  }

  if (j == 0) {
    float lS0 = logf(fmaxf(e0, 1e-30f));
    out[qstart + r0]         = (float)pa0;
    out[A + qstart + r0]     = spa0 - m0 - lS0;
    out[2 * A + qstart + r0] = lS0 - t0 / e0;
    if (v1) {
      float lS1 = logf(fmaxf(e1, 1e-30f));
      out[qstart + r1]         = (float)pa1;
      out[A + qstart + r1]     = spa1 - m1 - lS1;
      out[2 * A + qstart + r1] = lS1 - t1 / e1;
    }
  }
}

extern "C" void kernel_launch(void* const* d_in, const int* in_sizes, int n_in,
                              void* d_out, int out_size, void* d_ws, size_t ws_size,
                              hipStream_t stream) {
  const float* x  = (const float*)d_in[0];
  const float* Wq = (const float*)d_in[1];
  const float* bq = (const float*)d_in[2];
  const float* Wk = (const float*)d_in[3];
  const float* bk = (const float*)d_in[4];
  const int* actors       = (const int*)d_in[5];
  const int* qindices     = (const int*)d_in[6];
  const int* actees       = (const int*)d_in[7];
  const int* kindices     = (const int*)d_in[8];
  const int* prev_actions = (const int*)d_in[9];

  const int A = in_sizes[5];
  const int E = in_sizes[7];
  const int B = (out_size - 3 * A) / ENVSTRIDE;
  if (B <= 0) return;

  float* out = (float*)d_out;
  // 16B-aligned staging inside the logits region (each env uses 10240 < 16384 floats)
  float* stg = out + (((size_t)3 * A + 3) & ~(size_t)3);

  const int jobs = E + A;
  proj_kernel<<<dim3((jobs + ROWS - 1) / ROWS), dim3(256), 0, stream>>>(
      x, Wq, bq, Wk, bk, actors, qindices, actees, kindices, A, E, stg);
  logits_kernel<<<dim3(B), dim3(256), 0, stream>>>(
      qindices, kindices, prev_actions, stg, A, E, out);
}

// Round 6
// 90.825 us; speedup vs baseline: 1.5760x; 1.4850x over previous
//
#include <hip/hip_runtime.h>
#include <math.h>

#define MA 64
#define ME 256
#define DM 256
#define DQK 32
#define ENVSTRIDE (MA * ME)            // 16384 floats per env
#define MASKVAL -998244352.0f          // bf16-rounded -1e9 (matches reference)
#define QK_SCALE 0.17677669529663687f  // 1/sqrt(32)

__device__ __forceinline__ int lb(const int* __restrict__ a, int n, int v){
  int lo = 0, hi = n;
  while (lo < hi){ int mid = (lo + hi) >> 1; if (a[mid] < v) lo = mid + 1; else hi = mid; }
  return lo;
}
__device__ __forceinline__ float4 f4fma(float s, float4 a, float4 acc){
  acc.x = fmaf(s, a.x, acc.x); acc.y = fmaf(s, a.y, acc.y);
  acc.z = fmaf(s, a.z, acc.z); acc.w = fmaf(s, a.w, acc.w); return acc;
}
__device__ __forceinline__ float4 f4add(float4 a, float4 b){
  a.x += b.x; a.y += b.y; a.z += b.z; a.w += b.w; return a;
}
__device__ __forceinline__ float dot4(float4 a, float4 b){
  return a.x * b.x + a.y * b.y + a.z * b.z + a.w * b.w;
}

// ================= K1: projection. wave = 64 rows x 32 cols; W via scalar loads =================
// lane holds its x row in a rolling 4xfloat4 window; acc = 32 cols in 8 float4.
__global__ __launch_bounds__(256)
void proj_kernel(const float* __restrict__ x,
                 const float* __restrict__ Wq, const float* __restrict__ bq,
                 const float* __restrict__ Wk, const float* __restrict__ bk,
                 const int* __restrict__ actors, const int* __restrict__ qindices,
                 const int* __restrict__ actees, const int* __restrict__ kindices,
                 int A, int E, float* __restrict__ stage)
{
  const int lane = threadIdx.x & 63;
  int wid = blockIdx.x * 4 + (threadIdx.x >> 6);
  wid = __builtin_amdgcn_readfirstlane(wid);     // force wave-uniform for scalar W path
  const int nKw = (E + 63) >> 6;
  const int nQw = (A + 63) >> 6;
  if (wid >= nKw + nQw) return;

  const bool iskey = (wid < nKw);
  const int  base  = iskey ? (wid << 6) : ((wid - nKw) << 6);
  const int  n     = iskey ? E : A;
  const int  job   = base + lane;
  const bool valid = (job < n);
  const int  jc    = valid ? job : (n - 1);

  const int src = iskey ? actees[jc] : actors[jc];
  const float* __restrict__ Wb = iskey ? Wk : Wq;   // wave-uniform
  const float* __restrict__ bb = iskey ? bk : bq;

  const float4* __restrict__ xv4 = (const float4*)(x + (size_t)src * DM);

  float4 a0, a1, a2, a3, a4, a5, a6, a7;
  a0 = a1 = a2 = a3 = a4 = a5 = a6 = a7 = make_float4(0.f, 0.f, 0.f, 0.f);

  float4 c0 = xv4[0], c1 = xv4[1], c2 = xv4[2], c3 = xv4[3];
  float4 p0 = c0, p1 = c1, p2 = c2, p3 = c3;

#define STEP(s, jj) { const float4* wr = (const float4*)(Wb + ((mb << 4) + (jj)) * DQK); \
    a0 = f4fma((s), wr[0], a0); a1 = f4fma((s), wr[1], a1); \
    a2 = f4fma((s), wr[2], a2); a3 = f4fma((s), wr[3], a3); \
    a4 = f4fma((s), wr[4], a4); a5 = f4fma((s), wr[5], a5); \
    a6 = f4fma((s), wr[6], a6); a7 = f4fma((s), wr[7], a7); }

  for (int mb = 0; mb < 16; ++mb) {
    if (mb < 15) {                       // prefetch next 64B line of the row
      const float4* nx = xv4 + ((mb + 1) << 2);
      p0 = nx[0]; p1 = nx[1]; p2 = nx[2]; p3 = nx[3];
    }
    STEP(c0.x, 0)  STEP(c0.y, 1)  STEP(c0.z, 2)  STEP(c0.w, 3)
    STEP(c1.x, 4)  STEP(c1.y, 5)  STEP(c1.z, 6)  STEP(c1.w, 7)
    STEP(c2.x, 8)  STEP(c2.y, 9)  STEP(c2.z, 10) STEP(c2.w, 11)
    STEP(c3.x, 12) STEP(c3.y, 13) STEP(c3.z, 14) STEP(c3.w, 15)
    c0 = p0; c1 = p1; c2 = p2; c3 = p3;
  }
#undef STEP

  const float4* bv = (const float4*)bb;
  a0 = f4add(a0, bv[0]); a1 = f4add(a1, bv[1]); a2 = f4add(a2, bv[2]); a3 = f4add(a3, bv[3]);
  a4 = f4add(a4, bv[4]); a5 = f4add(a5, bv[5]); a6 = f4add(a6, bv[6]); a7 = f4add(a7, bv[7]);

  if (valid) {
    size_t dstoff;
    if (iskey) {
      const int idx = kindices[jc];
      dstoff = (size_t)(idx >> 8) * ENVSTRIDE + (size_t)(idx & (ME - 1)) * DQK;
    } else {
      const int idx = qindices[jc];
      dstoff = (size_t)(idx >> 6) * ENVSTRIDE + ME * DQK + (size_t)(idx & (MA - 1)) * DQK;
    }
    float4* dst = (float4*)(stage + dstoff);
    dst[0] = a0; dst[1] = a1; dst[2] = a2; dst[3] = a3;
    dst[4] = a4; dst[5] = a5; dst[6] = a6; dst[7] = a7;
  }
}

// ================= K2: logits + online softmax, one block per env (unchanged, passing) =================
__global__ __launch_bounds__(256, 3)
void logits_kernel(const int* __restrict__ qindices, const int* __restrict__ kindices,
                   const int* __restrict__ prev_actions, const float* __restrict__ stage,
                   int A, int E, float* __restrict__ out)
{
  __shared__ float kb[ME][DQK];      // XOR-swizzled float4 slots: conflict-free reads
  __shared__ int srange[4];

  const int t = threadIdx.x, b = blockIdx.x;

  if (t < 4) {
    const int* arr = (t < 2) ? qindices : kindices;
    const int  nn  = (t < 2) ? A : E;
    const int  vv  = (t == 0) ? b * MA : (t == 1) ? (b + 1) * MA
                   : (t == 2) ? b * ME : (b + 1) * ME;
    srange[t] = lb(arr, nn, vv);
  }
  __syncthreads();
  const int qstart = srange[0], qlen = srange[1] - srange[0];
  const int klen   = srange[3] - srange[2];

  const float* envst = stage + (size_t)b * ENVSTRIDE;

  #pragma unroll
  for (int i = 0; i < 8; ++i) {
    int f = t + i * 256;             // float4 index: row = f>>3, slot c = f&7
    int row = f >> 3, c = f & 7;
    if (row < klen)
      *(float4*)&kb[row][((c ^ (row & 7)) << 2)] = *(const float4*)(envst + f * 4);
  }

  const int j = t & 7, g = t >> 3;
  const int r0 = 2 * g, r1 = r0 + 1;
  const bool v0 = (r0 < qlen), v1 = (r1 < qlen);
  float4 qv0[8], qv1[8];
  {
    const float* qbase = envst + ME * DQK;
    const int r0s = v0 ? r0 : 0, r1s = v1 ? r1 : r0s;
    #pragma unroll
    for (int c = 0; c < 8; ++c) qv0[c] = *(const float4*)(qbase + r0s * DQK + c * 4);
    #pragma unroll
    for (int c = 0; c < 8; ++c) qv1[c] = *(const float4*)(qbase + r1s * DQK + c * 4);
  }
  int pa0 = v0 ? (prev_actions[qstart + r0] & (ME - 1)) : -1;
  int pa1 = v1 ? (prev_actions[qstart + r1] & (ME - 1)) : -1;

  __syncthreads();   // staging complete; safe to overwrite env region with logits

  float* out_lg = out + (size_t)3 * A + (size_t)b * ENVSTRIDE;

  if (!v0) {
    #pragma unroll
    for (int s = 0; s < 32; ++s) {
      out_lg[r0 * ME + j + 8 * s] = MASKVAL;
      out_lg[r1 * ME + j + 8 * s] = MASKVAL;
    }
    return;
  }

  float m0 = MASKVAL, e0 = 0.f, t0 = 0.f, spa0 = MASKVAL;
  float m1 = MASKVAL, e1 = 0.f, t1 = 0.f, spa1 = MASKVAL;

  for (int s = 0; s < 32; ++s) {
    const int k = j + 8 * s;
    const bool kval = (k < klen);
    float d0 = MASKVAL, d1 = MASKVAL;
    if (kval) {
      float a0 = 0.f, a1 = 0.f;
      #pragma unroll
      for (int c = 0; c < 8; ++c) {
        float4 kv = *(const float4*)&kb[k][((c ^ (k & 7)) << 2)];
        a0 += dot4(qv0[c], kv);
        a1 += dot4(qv1[c], kv);
      }
      d0 = a0 * QK_SCALE;
      d1 = v1 ? a1 * QK_SCALE : MASKVAL;
    }
    out_lg[r0 * ME + k] = d0;
    out_lg[r1 * ME + k] = d1;
    if (k == pa0) spa0 = d0;
    if (k == pa1) spa1 = d1;

    {
      float nm = fmaxf(m0, d0);
      float sc = expf(m0 - nm);
      float ed = kval ? expf(d0 - nm) : 0.f;
      t0 = (t0 + e0 * (m0 - nm)) * sc + ed * (d0 - nm);
      e0 = e0 * sc + ed;
      m0 = nm;
    }
    if (v1) {
      float nm = fmaxf(m1, d1);
      float sc = expf(m1 - nm);
      float ed = kval ? expf(d1 - nm) : 0.f;
      t1 = (t1 + e1 * (m1 - nm)) * sc + ed * (d1 - nm);
      e1 = e1 * sc + ed;
      m1 = nm;
    }
  }

  #pragma unroll
  for (int off = 1; off < 8; off <<= 1) {
    float om = __shfl_xor(m0, off), oe = __shfl_xor(e0, off), ot = __shfl_xor(t0, off);
    float M  = fmaxf(m0, om);
    float sa = expf(m0 - M), sb = expf(om - M);
    t0 = (t0 + e0 * (m0 - M)) * sa + (ot + oe * (om - M)) * sb;
    e0 = e0 * sa + oe * sb;
    m0 = M;
    spa0 = fmaxf(spa0, __shfl_xor(spa0, off));

    float om1 = __shfl_xor(m1, off), oe1 = __shfl_xor(e1, off), ot1 = __shfl_xor(t1, off);
    float M1  = fmaxf(m1, om1);
    float sa1 = expf(m1 - M1), sb1 = expf(om1 - M1);
    t1 = (t1 + e1 * (m1 - M1)) * sa1 + (ot1 + oe1 * (om1 - M1)) * sb1;
    e1 = e1 * sa1 + oe1 * sb1;
    m1 = M1;
    spa1 = fmaxf(spa1, __shfl_xor(spa1, off));
  }

  if (j == 0) {
    float lS0 = logf(fmaxf(e0, 1e-30f));
    out[qstart + r0]         = (float)pa0;
    out[A + qstart + r0]     = spa0 - m0 - lS0;
    out[2 * A + qstart + r0] = lS0 - t0 / e0;
    if (v1) {
      float lS1 = logf(fmaxf(e1, 1e-30f));
      out[qstart + r1]         = (float)pa1;
      out[A + qstart + r1]     = spa1 - m1 - lS1;
      out[2 * A + qstart + r1] = lS1 - t1 / e1;
    }
  }
}

extern "C" void kernel_launch(void* const* d_in, const int* in_sizes, int n_in,
                              void* d_out, int out_size, void* d_ws, size_t ws_size,
                              hipStream_t stream) {
  const float* x  = (const float*)d_in[0];
  const float* Wq = (const float*)d_in[1];
  const float* bq = (const float*)d_in[2];
  const float* Wk = (const float*)d_in[3];
  const float* bk = (const float*)d_in[4];
  const int* actors       = (const int*)d_in[5];
  const int* qindices     = (const int*)d_in[6];
  const int* actees       = (const int*)d_in[7];
  const int* kindices     = (const int*)d_in[8];
  const int* prev_actions = (const int*)d_in[9];

  const int A = in_sizes[5];
  const int E = in_sizes[7];
  const int B = (out_size - 3 * A) / ENVSTRIDE;
  if (B <= 0) return;

  float* out = (float*)d_out;
  // 16B-aligned staging inside the logits region (each env uses 10240 < 16384 floats)
  float* stg = out + (((size_t)3 * A + 3) & ~(size_t)3);

  const int nKw = (E + 63) / 64;
  const int nQw = (A + 63) / 64;
  const int nblk = (nKw + nQw + 3) / 4;

  proj_kernel<<<dim3(nblk), dim3(256), 0, stream>>>(
      x, Wq, bq, Wk, bk, actors, qindices, actees, kindices, A, E, stg);
  logits_kernel<<<dim3(B), dim3(256), 0, stream>>>(
      qindices, kindices, prev_actions, stg, A, E, out);
}

// Round 7
// 83.252 us; speedup vs baseline: 1.7193x; 1.0910x over previous
//
#include <hip/hip_runtime.h>
#include <math.h>

#define MA 64
#define ME 256
#define DM 256
#define DQK 32
#define ENVSTRIDE (MA * ME)            // 16384 floats per env
#define MASKVAL -998244352.0f          // bf16-rounded -1e9 (matches reference)
#define QK_SCALE 0.17677669529663687f  // 1/sqrt(32)
#define RSTR 36                        // partial-row stride (144B, 16B-aligned)

__device__ __forceinline__ int lb(const int* __restrict__ a, int n, int v){
  int lo = 0, hi = n;
  while (lo < hi){ int mid = (lo + hi) >> 1; if (a[mid] < v) lo = mid + 1; else hi = mid; }
  return lo;
}
__device__ __forceinline__ float4 f4fma(float s, float4 a, float4 acc){
  acc.x = fmaf(s, a.x, acc.x); acc.y = fmaf(s, a.y, acc.y);
  acc.z = fmaf(s, a.z, acc.z); acc.w = fmaf(s, a.w, acc.w); return acc;
}
__device__ __forceinline__ float4 f4add(float4 a, float4 b){
  a.x += b.x; a.y += b.y; a.z += b.z; a.w += b.w; return a;
}
__device__ __forceinline__ float dot4(float4 a, float4 b){
  return a.x * b.x + a.y * b.y + a.z * b.z + a.w * b.w;
}

// ========== K1: projection, split-K. Block = 64 rows x 4 K-quarter waves ==========
// lane = row; wave w does K in [64w, 64w+64); W via wave-uniform scalar loads.
__global__ __launch_bounds__(256)
void proj_kernel(const float* __restrict__ x,
                 const float* __restrict__ Wq, const float* __restrict__ bq,
                 const float* __restrict__ Wk, const float* __restrict__ bk,
                 const int* __restrict__ actors, const int* __restrict__ qindices,
                 const int* __restrict__ actees, const int* __restrict__ kindices,
                 int A, int E, int nKblk, float* __restrict__ stage)
{
  __shared__ float red[4][64][RSTR];   // 36864 B of K-split partials

  const int t    = threadIdx.x;
  const int lane = t & 63;
  const int w    = __builtin_amdgcn_readfirstlane(t >> 6);  // provably wave-uniform

  const bool iskey = ((int)blockIdx.x < nKblk);
  const int  base  = (iskey ? (int)blockIdx.x : ((int)blockIdx.x - nKblk)) << 6;
  const int  n     = iskey ? E : A;
  const int  job   = base + lane;
  const int  jc    = min(job, n - 1);
  const int  src   = iskey ? actees[jc] : actors[jc];
  const float* __restrict__ Wb = iskey ? Wk : Wq;           // uniform -> s_load path

  const float4* __restrict__ xv4 = (const float4*)(x + (size_t)src * DM + (w << 6));

  float4 a0, a1, a2, a3, a4, a5, a6, a7;
  a0 = a1 = a2 = a3 = a4 = a5 = a6 = a7 = make_float4(0.f, 0.f, 0.f, 0.f);

  float4 c0 = xv4[0], c1 = xv4[1], c2 = xv4[2], c3 = xv4[3];

#define STEP(sv, mi) { const float4* wr = (const float4*)(Wb + (size_t)(mi) * DQK); \
    a0 = f4fma((sv), wr[0], a0); a1 = f4fma((sv), wr[1], a1); \
    a2 = f4fma((sv), wr[2], a2); a3 = f4fma((sv), wr[3], a3); \
    a4 = f4fma((sv), wr[4], a4); a5 = f4fma((sv), wr[5], a5); \
    a6 = f4fma((sv), wr[6], a6); a7 = f4fma((sv), wr[7], a7); }

  #pragma unroll
  for (int mb = 0; mb < 4; ++mb) {
    float4 p0, p1, p2, p3;
    if (mb < 3) {                      // prefetch next 64B slice of this lane's row
      const float4* nx = xv4 + ((mb + 1) << 2);
      p0 = nx[0]; p1 = nx[1]; p2 = nx[2]; p3 = nx[3];
    }
    const int mbase = (w << 6) + (mb << 4);
    STEP(c0.x, mbase + 0)  STEP(c0.y, mbase + 1)  STEP(c0.z, mbase + 2)  STEP(c0.w, mbase + 3)
    STEP(c1.x, mbase + 4)  STEP(c1.y, mbase + 5)  STEP(c1.z, mbase + 6)  STEP(c1.w, mbase + 7)
    STEP(c2.x, mbase + 8)  STEP(c2.y, mbase + 9)  STEP(c2.z, mbase + 10) STEP(c2.w, mbase + 11)
    STEP(c3.x, mbase + 12) STEP(c3.y, mbase + 13) STEP(c3.z, mbase + 14) STEP(c3.w, mbase + 15)
    if (mb < 3) { c0 = p0; c1 = p1; c2 = p2; c3 = p3; }
  }
#undef STEP

  {
    float4* rp = (float4*)&red[w][lane][0];
    rp[0] = a0; rp[1] = a1; rp[2] = a2; rp[3] = a3;
    rp[4] = a4; rp[5] = a5; rp[6] = a6; rp[7] = a7;
  }
  __syncthreads();

  // ---- reduce 4 partials + bias, scatter to stage; thread t owns 2 (row, col4) slots ----
  #pragma unroll
  for (int i = 0; i < 2; ++i) {
    const int fi  = t * 2 + i;
    const int row = fi >> 3, c = fi & 7;
    const int jobr = base + row;
    if (jobr < n) {
      float4 s  = *(float4*)&red[0][row][c * 4];
      float4 s1 = *(float4*)&red[1][row][c * 4];
      float4 s2 = *(float4*)&red[2][row][c * 4];
      float4 s3 = *(float4*)&red[3][row][c * 4];
      s = f4add(f4add(s, s1), f4add(s2, s3));
      const float* bb = iskey ? bk : bq;
      s = f4add(s, *(const float4*)(bb + c * 4));
      const int idx = iskey ? kindices[jobr] : qindices[jobr];
      size_t dstoff = iskey
        ? (size_t)(idx >> 8) * ENVSTRIDE + (size_t)(idx & (ME - 1)) * DQK
        : (size_t)(idx >> 6) * ENVSTRIDE + ME * DQK + (size_t)(idx & (MA - 1)) * DQK;
      *(float4*)(stage + dstoff + c * 4) = s;
    }
  }
}

// ========== K2: logits + online softmax, one block per env (unchanged, passing) ==========
__global__ __launch_bounds__(256, 3)
void logits_kernel(const int* __restrict__ qindices, const int* __restrict__ kindices,
                   const int* __restrict__ prev_actions, const float* __restrict__ stage,
                   int A, int E, float* __restrict__ out)
{
  __shared__ float kb[ME][DQK];      // XOR-swizzled float4 slots: conflict-free reads
  __shared__ int srange[4];

  const int t = threadIdx.x, b = blockIdx.x;

  if (t < 4) {
    const int* arr = (t < 2) ? qindices : kindices;
    const int  nn  = (t < 2) ? A : E;
    const int  vv  = (t == 0) ? b * MA : (t == 1) ? (b + 1) * MA
                   : (t == 2) ? b * ME : (b + 1) * ME;
    srange[t] = lb(arr, nn, vv);
  }
  __syncthreads();
  const int qstart = srange[0], qlen = srange[1] - srange[0];
  const int klen   = srange[3] - srange[2];

  const float* envst = stage + (size_t)b * ENVSTRIDE;

  #pragma unroll
  for (int i = 0; i < 8; ++i) {
    int f = t + i * 256;             // float4 index: row = f>>3, slot c = f&7
    int row = f >> 3, c = f & 7;
    if (row < klen)
      *(float4*)&kb[row][((c ^ (row & 7)) << 2)] = *(const float4*)(envst + f * 4);
  }

  const int j = t & 7, g = t >> 3;
  const int r0 = 2 * g, r1 = r0 + 1;
  const bool v0 = (r0 < qlen), v1 = (r1 < qlen);
  float4 qv0[8], qv1[8];
  {
    const float* qbase = envst + ME * DQK;
    const int r0s = v0 ? r0 : 0, r1s = v1 ? r1 : r0s;
    #pragma unroll
    for (int c = 0; c < 8; ++c) qv0[c] = *(const float4*)(qbase + r0s * DQK + c * 4);
    #pragma unroll
    for (int c = 0; c < 8; ++c) qv1[c] = *(const float4*)(qbase + r1s * DQK + c * 4);
  }
  int pa0 = v0 ? (prev_actions[qstart + r0] & (ME - 1)) : -1;
  int pa1 = v1 ? (prev_actions[qstart + r1] & (ME - 1)) : -1;

  __syncthreads();   // staging complete; safe to overwrite env region with logits

  float* out_lg = out + (size_t)3 * A + (size_t)b * ENVSTRIDE;

  if (!v0) {
    #pragma unroll
    for (int s = 0; s < 32; ++s) {
      out_lg[r0 * ME + j + 8 * s] = MASKVAL;
      out_lg[r1 * ME + j + 8 * s] = MASKVAL;
    }
    return;
  }

  float m0 = MASKVAL, e0 = 0.f, t0 = 0.f, spa0 = MASKVAL;
  float m1 = MASKVAL, e1 = 0.f, t1 = 0.f, spa1 = MASKVAL;

  for (int s = 0; s < 32; ++s) {
    const int k = j + 8 * s;
    const bool kval = (k < klen);
    float d0 = MASKVAL, d1 = MASKVAL;
    if (kval) {
      float a0 = 0.f, a1 = 0.f;
      #pragma unroll
      for (int c = 0; c < 8; ++c) {
        float4 kv = *(const float4*)&kb[k][((c ^ (k & 7)) << 2)];
        a0 += dot4(qv0[c], kv);
        a1 += dot4(qv1[c], kv);
      }
      d0 = a0 * QK_SCALE;
      d1 = v1 ? a1 * QK_SCALE : MASKVAL;
    }
    out_lg[r0 * ME + k] = d0;
    out_lg[r1 * ME + k] = d1;
    if (k == pa0) spa0 = d0;
    if (k == pa1) spa1 = d1;

    {
      float nm = fmaxf(m0, d0);
      float sc = expf(m0 - nm);
      float ed = kval ? expf(d0 - nm) : 0.f;
      t0 = (t0 + e0 * (m0 - nm)) * sc + ed * (d0 - nm);
      e0 = e0 * sc + ed;
      m0 = nm;
    }
    if (v1) {
      float nm = fmaxf(m1, d1);
      float sc = expf(m1 - nm);
      float ed = kval ? expf(d1 - nm) : 0.f;
      t1 = (t1 + e1 * (m1 - nm)) * sc + ed * (d1 - nm);
      e1 = e1 * sc + ed;
      m1 = nm;
    }
  }

  #pragma unroll
  for (int off = 1; off < 8; off <<= 1) {
    float om = __shfl_xor(m0, off), oe = __shfl_xor(e0, off), ot = __shfl_xor(t0, off);
    float M  = fmaxf(m0, om);
    float sa = expf(m0 - M), sb = expf(om - M);
    t0 = (t0 + e0 * (m0 - M)) * sa + (ot + oe * (om - M)) * sb;
    e0 = e0 * sa + oe * sb;
    m0 = M;
    spa0 = fmaxf(spa0, __shfl_xor(spa0, off));

    float om1 = __shfl_xor(m1, off), oe1 = __shfl_xor(e1, off), ot1 = __shfl_xor(t1, off);
    float M1  = fmaxf(m1, om1);
    float sa1 = expf(m1 - M1), sb1 = expf(om1 - M1);
    t1 = (t1 + e1 * (m1 - M1)) * sa1 + (ot1 + oe1 * (om1 - M1)) * sb1;
    e1 = e1 * sa1 + oe1 * sb1;
    m1 = M1;
    spa1 = fmaxf(spa1, __shfl_xor(spa1, off));
  }

  if (j == 0) {
    float lS0 = logf(fmaxf(e0, 1e-30f));
    out[qstart + r0]         = (float)pa0;
    out[A + qstart + r0]     = spa0 - m0 - lS0;
    out[2 * A + qstart + r0] = lS0 - t0 / e0;
    if (v1) {
      float lS1 = logf(fmaxf(e1, 1e-30f));
      out[qstart + r1]         = (float)pa1;
      out[A + qstart + r1]     = spa1 - m1 - lS1;
      out[2 * A + qstart + r1] = lS1 - t1 / e1;
    }
  }
}

extern "C" void kernel_launch(void* const* d_in, const int* in_sizes, int n_in,
                              void* d_out, int out_size, void* d_ws, size_t ws_size,
                              hipStream_t stream) {
  const float* x  = (const float*)d_in[0];
  const float* Wq = (const float*)d_in[1];
  const float* bq = (const float*)d_in[2];
  const float* Wk = (const float*)d_in[3];
  const float* bk = (const float*)d_in[4];
  const int* actors       = (const int*)d_in[5];
  const int* qindices     = (const int*)d_in[6];
  const int* actees       = (const int*)d_in[7];
  const int* kindices     = (const int*)d_in[8];
  const int* prev_actions = (const int*)d_in[9];

  const int A = in_sizes[5];
  const int E = in_sizes[7];
  const int B = (out_size - 3 * A) / ENVSTRIDE;
  if (B <= 0) return;

  float* out = (float*)d_out;
  // 16B-aligned staging inside the logits region (each env uses 10240 < 16384 floats)
  float* stg = out + (((size_t)3 * A + 3) & ~(size_t)3);

  const int nKblk = (E + 63) / 64;
  const int nQblk = (A + 63) / 64;

  proj_kernel<<<dim3(nKblk + nQblk), dim3(256), 0, stream>>>(
      x, Wq, bq, Wk, bk, actors, qindices, actees, kindices, A, E, nKblk, stg);
  logits_kernel<<<dim3(B), dim3(256), 0, stream>>>(
      qindices, kindices, prev_actions, stg, A, E, out);
}

// Round 8
// 67.247 us; speedup vs baseline: 2.1285x; 1.2380x over previous
//
#include <hip/hip_runtime.h>
#include <math.h>

#define MA 64
#define ME 256
#define DM 256
#define DQK 32
#define ENVSTRIDE (MA * ME)            // 16384 floats per env
#define MASKVAL -998244352.0f          // bf16-rounded -1e9 (matches reference)
#define QK_SCALE 0.17677669529663687f  // 1/sqrt(32)

typedef __attribute__((ext_vector_type(8))) short bf16x8;
typedef __attribute__((ext_vector_type(4))) float f32x4;

__device__ __forceinline__ int lb(const int* __restrict__ a, int n, int v){
  int lo = 0, hi = n;
  while (lo < hi){ int mid = (lo + hi) >> 1; if (a[mid] < v) lo = mid + 1; else hi = mid; }
  return lo;
}
__device__ __forceinline__ float dot4(float4 a, float4 b){
  return a.x * b.x + a.y * b.y + a.z * b.z + a.w * b.w;
}
// pack two f32 -> two bf16 (round-half-up; bias cancels over random-sign products)
__device__ __forceinline__ unsigned pk2bf(float lo, float hi){
  unsigned ul = __float_as_uint(lo) + 0x8000u;
  unsigned uh = __float_as_uint(hi) + 0x8000u;
  return (ul >> 16) | (uh & 0xFFFF0000u);
}

// ========== K1: MFMA projection. 1 wave = 64 rows; W in register B-fragments ==========
__global__ __launch_bounds__(64)
void proj_mfma(const float* __restrict__ x,
               const float* __restrict__ Wq, const float* __restrict__ bq,
               const float* __restrict__ Wk, const float* __restrict__ bk,
               const int* __restrict__ actors, const int* __restrict__ qindices,
               const int* __restrict__ actees, const int* __restrict__ kindices,
               int A, int E, int nKblk, float* __restrict__ stage)
{
  const int lane = threadIdx.x;
  const bool iskey = ((int)blockIdx.x < nKblk);
  const int  base  = (iskey ? (int)blockIdx.x : ((int)blockIdx.x - nKblk)) << 6;
  const int  n     = iskey ? E : A;
  const float* __restrict__ Wb = iskey ? Wk : Wq;
  const float* __restrict__ bb = iskey ? bk : bq;
  const int* __restrict__ srcinds = iskey ? actees : actors;
  const int* __restrict__ posinds = iskey ? kindices : qindices;

  const int lr = lane & 15;        // A-row / B-col / D-col within tile
  const int lq = lane >> 4;        // K-quarter selector

  // ---- preload all B fragments (W): 8 K-steps x 2 N-tiles, packed bf16 ----
  bf16x8 bfrag[8][2];
  #pragma unroll
  for (int kk = 0; kk < 8; ++kk) {
    const int k0 = kk * 32 + lq * 8;
    #pragma unroll
    for (int nt = 0; nt < 2; ++nt) {
      const float* wp = Wb + (size_t)k0 * DQK + nt * 16 + lr;
      union { unsigned u[4]; bf16x8 v; } fb;
      #pragma unroll
      for (int p = 0; p < 4; ++p)
        fb.u[p] = pk2bf(wp[(2 * p) * DQK], wp[(2 * p + 1) * DQK]);
      bfrag[kk][nt] = fb.v;
    }
  }
  const float bv0 = bb[lr];
  const float bv1 = bb[16 + lr];

  #pragma unroll
  for (int mt = 0; mt < 4; ++mt) {
    const int rbase = base + mt * 16;
    if (rbase >= n) break;
    const int arow = min(rbase + lr, n - 1);
    const int src  = srcinds[arow];
    const float* xr = x + (size_t)src * DM + lq * 8;

    f32x4 acc0 = {bv0, bv0, bv0, bv0};   // bias folded into accumulator init
    f32x4 acc1 = {bv1, bv1, bv1, bv1};
    #pragma unroll
    for (int kk = 0; kk < 8; ++kk) {
      float4 c0 = *(const float4*)(xr + kk * 32);
      float4 c1 = *(const float4*)(xr + kk * 32 + 4);
      union { unsigned u[4]; bf16x8 v; } fa;
      fa.u[0] = pk2bf(c0.x, c0.y); fa.u[1] = pk2bf(c0.z, c0.w);
      fa.u[2] = pk2bf(c1.x, c1.y); fa.u[3] = pk2bf(c1.z, c1.w);
      acc0 = __builtin_amdgcn_mfma_f32_16x16x32_bf16(fa.v, bfrag[kk][0], acc0, 0, 0, 0);
      acc1 = __builtin_amdgcn_mfma_f32_16x16x32_bf16(fa.v, bfrag[kk][1], acc1, 0, 0, 0);
    }

    // D: col = lane&15, row = 4*(lane>>4) + reg  (m89-verified mapping)
    #pragma unroll
    for (int reg = 0; reg < 4; ++reg) {
      const int jobr = rbase + lq * 4 + reg;
      if (jobr < n) {
        const int idx = posinds[jobr];
        size_t off = iskey
          ? (size_t)(idx >> 8) * ENVSTRIDE + (size_t)(idx & (ME - 1)) * DQK
          : (size_t)(idx >> 6) * ENVSTRIDE + ME * DQK + (size_t)(idx & (MA - 1)) * DQK;
        stage[off + lr]      = acc0[reg];
        stage[off + 16 + lr] = acc1[reg];
      }
    }
  }
}

// ========== K2: logits + online softmax, one block per env (unchanged, verified) ==========
__global__ __launch_bounds__(256, 3)
void logits_kernel(const int* __restrict__ qindices, const int* __restrict__ kindices,
                   const int* __restrict__ prev_actions, const float* __restrict__ stage,
                   int A, int E, float* __restrict__ out)
{
  __shared__ float kb[ME][DQK];      // XOR-swizzled float4 slots: conflict-free reads
  __shared__ int srange[4];

  const int t = threadIdx.x, b = blockIdx.x;

  if (t < 4) {
    const int* arr = (t < 2) ? qindices : kindices;
    const int  nn  = (t < 2) ? A : E;
    const int  vv  = (t == 0) ? b * MA : (t == 1) ? (b + 1) * MA
                   : (t == 2) ? b * ME : (b + 1) * ME;
    srange[t] = lb(arr, nn, vv);
  }
  __syncthreads();
  const int qstart = srange[0], qlen = srange[1] - srange[0];
  const int klen   = srange[3] - srange[2];

  const float* envst = stage + (size_t)b * ENVSTRIDE;

  #pragma unroll
  for (int i = 0; i < 8; ++i) {
    int f = t + i * 256;             // float4 index: row = f>>3, slot c = f&7
    int row = f >> 3, c = f & 7;
    if (row < klen)
      *(float4*)&kb[row][((c ^ (row & 7)) << 2)] = *(const float4*)(envst + f * 4);
  }

  const int j = t & 7, g = t >> 3;
  const int r0 = 2 * g, r1 = r0 + 1;
  const bool v0 = (r0 < qlen), v1 = (r1 < qlen);
  float4 qv0[8], qv1[8];
  {
    const float* qbase = envst + ME * DQK;
    const int r0s = v0 ? r0 : 0, r1s = v1 ? r1 : r0s;
    #pragma unroll
    for (int c = 0; c < 8; ++c) qv0[c] = *(const float4*)(qbase + r0s * DQK + c * 4);
    #pragma unroll
    for (int c = 0; c < 8; ++c) qv1[c] = *(const float4*)(qbase + r1s * DQK + c * 4);
  }
  int pa0 = v0 ? (prev_actions[qstart + r0] & (ME - 1)) : -1;
  int pa1 = v1 ? (prev_actions[qstart + r1] & (ME - 1)) : -1;

  __syncthreads();   // staging complete; safe to overwrite env region with logits

  float* out_lg = out + (size_t)3 * A + (size_t)b * ENVSTRIDE;

  if (!v0) {
    #pragma unroll
    for (int s = 0; s < 32; ++s) {
      out_lg[r0 * ME + j + 8 * s] = MASKVAL;
      out_lg[r1 * ME + j + 8 * s] = MASKVAL;
    }
    return;
  }

  float m0 = MASKVAL, e0 = 0.f, t0 = 0.f, spa0 = MASKVAL;
  float m1 = MASKVAL, e1 = 0.f, t1 = 0.f, spa1 = MASKVAL;

  for (int s = 0; s < 32; ++s) {
    const int k = j + 8 * s;
    const bool kval = (k < klen);
    float d0 = MASKVAL, d1 = MASKVAL;
    if (kval) {
      float a0 = 0.f, a1 = 0.f;
      #pragma unroll
      for (int c = 0; c < 8; ++c) {
        float4 kv = *(const float4*)&kb[k][((c ^ (k & 7)) << 2)];
        a0 += dot4(qv0[c], kv);
        a1 += dot4(qv1[c], kv);
      }
      d0 = a0 * QK_SCALE;
      d1 = v1 ? a1 * QK_SCALE : MASKVAL;
    }
    out_lg[r0 * ME + k] = d0;
    out_lg[r1 * ME + k] = d1;
    if (k == pa0) spa0 = d0;
    if (k == pa1) spa1 = d1;

    {
      float nm = fmaxf(m0, d0);
      float sc = expf(m0 - nm);
      float ed = kval ? expf(d0 - nm) : 0.f;
      t0 = (t0 + e0 * (m0 - nm)) * sc + ed * (d0 - nm);
      e0 = e0 * sc + ed;
      m0 = nm;
    }
    if (v1) {
      float nm = fmaxf(m1, d1);
      float sc = expf(m1 - nm);
      float ed = kval ? expf(d1 - nm) : 0.f;
      t1 = (t1 + e1 * (m1 - nm)) * sc + ed * (d1 - nm);
      e1 = e1 * sc + ed;
      m1 = nm;
    }
  }

  #pragma unroll
  for (int off = 1; off < 8; off <<= 1) {
    float om = __shfl_xor(m0, off), oe = __shfl_xor(e0, off), ot = __shfl_xor(t0, off);
    float M  = fmaxf(m0, om);
    float sa = expf(m0 - M), sb = expf(om - M);
    t0 = (t0 + e0 * (m0 - M)) * sa + (ot + oe * (om - M)) * sb;
    e0 = e0 * sa + oe * sb;
    m0 = M;
    spa0 = fmaxf(spa0, __shfl_xor(spa0, off));

    float om1 = __shfl_xor(m1, off), oe1 = __shfl_xor(e1, off), ot1 = __shfl_xor(t1, off);
    float M1  = fmaxf(m1, om1);
    float sa1 = expf(m1 - M1), sb1 = expf(om1 - M1);
    t1 = (t1 + e1 * (m1 - M1)) * sa1 + (ot1 + oe1 * (om1 - M1)) * sb1;
    e1 = e1 * sa1 + oe1 * sb1;
    m1 = M1;
    spa1 = fmaxf(spa1, __shfl_xor(spa1, off));
  }

  if (j == 0) {
    float lS0 = logf(fmaxf(e0, 1e-30f));
    out[qstart + r0]         = (float)pa0;
    out[A + qstart + r0]     = spa0 - m0 - lS0;
    out[2 * A + qstart + r0] = lS0 - t0 / e0;
    if (v1) {
      float lS1 = logf(fmaxf(e1, 1e-30f));
      out[qstart + r1]         = (float)pa1;
      out[A + qstart + r1]     = spa1 - m1 - lS1;
      out[2 * A + qstart + r1] = lS1 - t1 / e1;
    }
  }
}

extern "C" void kernel_launch(void* const* d_in, const int* in_sizes, int n_in,
                              void* d_out, int out_size, void* d_ws, size_t ws_size,
                              hipStream_t stream) {
  const float* x  = (const float*)d_in[0];
  const float* Wq = (const float*)d_in[1];
  const float* bq = (const float*)d_in[2];
  const float* Wk = (const float*)d_in[3];
  const float* bk = (const float*)d_in[4];
  const int* actors       = (const int*)d_in[5];
  const int* qindices     = (const int*)d_in[6];
  const int* actees       = (const int*)d_in[7];
  const int* kindices     = (const int*)d_in[8];
  const int* prev_actions = (const int*)d_in[9];

  const int A = in_sizes[5];
  const int E = in_sizes[7];
  const int B = (out_size - 3 * A) / ENVSTRIDE;
  if (B <= 0) return;

  float* out = (float*)d_out;
  // 16B-aligned staging inside the logits region (each env uses 10240 < 16384 floats)
  float* stg = out + (((size_t)3 * A + 3) & ~(size_t)3);

  const int nKblk = (E + 63) / 64;
  const int nQblk = (A + 63) / 64;

  proj_mfma<<<dim3(nKblk + nQblk), dim3(64), 0, stream>>>(
      x, Wq, bq, Wk, bk, actors, qindices, actees, kindices, A, E, nKblk, stg);
  logits_kernel<<<dim3(B), dim3(256), 0, stream>>>(
      qindices, kindices, prev_actions, stg, A, E, out);
}

// Round 9
// 41.278 us; speedup vs baseline: 3.4676x; 1.6291x over previous
//
#include <hip/hip_runtime.h>
#include <math.h>

#define MA 64
#define ME 256
#define DM 256
#define DQK 32
#define ENVSTRIDE (MA * ME)            // 16384 floats per env
#define MASKVAL -998244352.0f          // bf16-rounded -1e9 (matches reference)
#define QK_SCALE 0.17677669529663687f  // 1/sqrt(32)
#define KSTR 40                        // LDS row stride in ushorts (80B = 16B*5 -> conflict-free b128)

typedef __attribute__((ext_vector_type(8))) short bf16x8;
typedef __attribute__((ext_vector_type(4))) float f32x4;
typedef unsigned short u16;

__device__ __forceinline__ int lb(const int* __restrict__ a, int n, int v){
  int lo = 0, hi = n;
  while (lo < hi){ int mid = (lo + hi) >> 1; if (a[mid] < v) lo = mid + 1; else hi = mid; }
  return lo;
}
// round-to-nearest-even f32 -> bf16
__device__ __forceinline__ unsigned pk2bf(float lo, float hi){
  unsigned ul = __float_as_uint(lo); ul = ul + 0x7FFFu + ((ul >> 16) & 1u);
  unsigned uh = __float_as_uint(hi); uh = uh + 0x7FFFu + ((uh >> 16) & 1u);
  return (ul >> 16) | (uh & 0xFFFF0000u);
}
__device__ __forceinline__ u16 f2bu(float f){
  unsigned u = __float_as_uint(f);
  return (u16)((u + 0x7FFFu + ((u >> 16) & 1u)) >> 16);
}

// preload W [256x32] as 8 K-step x 2 N-tile B-fragments (validated layout, round 8)
__device__ __forceinline__ void load_wfrag(const float* __restrict__ W, int lr, int lq,
                                           bf16x8 (*bfr)[2]){
  #pragma unroll
  for (int kk = 0; kk < 8; ++kk) {
    const int k0 = kk * 32 + lq * 8;
    #pragma unroll
    for (int nt = 0; nt < 2; ++nt) {
      const float* wp = W + (size_t)k0 * DQK + nt * 16 + lr;
      union { unsigned u[4]; bf16x8 v; } fb;
      #pragma unroll
      for (int p = 0; p < 4; ++p) fb.u[p] = pk2bf(wp[(2*p)*DQK], wp[(2*p+1)*DQK]);
      bfr[kk][nt] = fb.v;
    }
  }
}

// project one 16-row tile: gather x rows, 16 MFMAs, store bf16 to LDS
__device__ __forceinline__ void proj_tile(const float* __restrict__ x,
                                          const int* __restrict__ gath, int start, int len,
                                          int rbase, int lr, int lq,
                                          const bf16x8 (*bfr)[2], float bv0, float bv1,
                                          u16* __restrict__ dst){
  const int arow = start + min(rbase + lr, len - 1);
  const float* xr = x + (size_t)gath[arow] * DM + lq * 8;
  f32x4 a0 = {bv0, bv0, bv0, bv0}, a1 = {bv1, bv1, bv1, bv1};
  #pragma unroll
  for (int kk = 0; kk < 8; ++kk) {
    float4 c0 = *(const float4*)(xr + kk * 32);
    float4 c1 = *(const float4*)(xr + kk * 32 + 4);
    union { unsigned u[4]; bf16x8 v; } fa;
    fa.u[0] = pk2bf(c0.x, c0.y); fa.u[1] = pk2bf(c0.z, c0.w);
    fa.u[2] = pk2bf(c1.x, c1.y); fa.u[3] = pk2bf(c1.z, c1.w);
    a0 = __builtin_amdgcn_mfma_f32_16x16x32_bf16(fa.v, bfr[kk][0], a0, 0, 0, 0);
    a1 = __builtin_amdgcn_mfma_f32_16x16x32_bf16(fa.v, bfr[kk][1], a1, 0, 0, 0);
  }
  // D: col = lane&15, row = 4*(lane>>4)+reg (validated round 8)
  #pragma unroll
  for (int reg = 0; reg < 4; ++reg) {
    const int row = rbase + 4 * lq + reg;
    if (row < len) {
      dst[row * KSTR + lr]      = f2bu(a0[reg]);
      dst[row * KSTR + 16 + lr] = f2bu(a1[reg]);
    }
  }
}

__global__ __launch_bounds__(256)
void fused_env(const float* __restrict__ x,  const float* __restrict__ Wq, const float* __restrict__ bq,
               const float* __restrict__ Wk, const float* __restrict__ bk,
               const int* __restrict__ actors, const int* __restrict__ qindices,
               const int* __restrict__ actees, const int* __restrict__ kindices,
               const int* __restrict__ prev_actions, int A, int E, float* __restrict__ out)
{
  __shared__ u16 kb[ME * KSTR];    // 20480 B, bf16 keys
  __shared__ u16 qsm[MA * KSTR];   //  5120 B, bf16 queries
  __shared__ int srange[4];

  const int t = threadIdx.x, b = blockIdx.x;
  if (t < 4) {
    const int* arr = (t < 2) ? qindices : kindices;
    const int nn = (t < 2) ? A : E;
    const int vv = (t == 0) ? b * MA : (t == 1) ? (b + 1) * MA
                 : (t == 2) ? b * ME : (b + 1) * ME;
    srange[t] = lb(arr, nn, vv);
  }
  __syncthreads();
  const int qstart = srange[0], qlen = srange[1] - srange[0];
  const int kstart = srange[2], klen = srange[3] - srange[2];

  const int lane = t & 63, w = t >> 6;
  const int lr = lane & 15, lq = lane >> 4;

  // ===== K projection: wave w handles tiles rbase = 16w + 64i (interleaved for balance) =====
  if (16 * w < klen) {
    bf16x8 bfr[8][2];
    load_wfrag(Wk, lr, lq, bfr);
    const float bv0 = bk[lr], bv1 = bk[16 + lr];
    #pragma unroll
    for (int i = 0; i < 4; ++i) {
      const int rbase = 16 * w + 64 * i;
      if (rbase < klen)
        proj_tile(x, actees, kstart, klen, rbase, lr, lq, bfr, bv0, bv1, kb);
    }
  }
  // ===== Q projection: wave w handles tile rbase = 16w =====
  if (16 * w < qlen) {
    bf16x8 bfr[8][2];
    load_wfrag(Wq, lr, lq, bfr);
    proj_tile(x, actors, qstart, qlen, 16 * w, lr, lq, bfr, bq[lr], bq[16 + lr], qsm);
  }
  __syncthreads();

  // ===== logits: wave w owns M-tile w (q rows 16w..16w+15), all 256 key cols =====
  float* out_lg = out + (size_t)3 * A + (size_t)b * ENVSTRIDE;
  const int row0 = 16 * w;

  if (row0 >= qlen) {          // fully padded rows: MASKVAL fill, coalesced float4
    const float4 mv = make_float4(MASKVAL, MASKVAL, MASKVAL, MASKVAL);
    float4* o4 = (float4*)out_lg;
    #pragma unroll
    for (int rr = 0; rr < 16; ++rr) o4[(row0 + rr) * 64 + lane] = mv;
    return;
  }

  const bf16x8 afr = *(const bf16x8*)&qsm[(row0 + lr) * KSTR + lq * 8];
  f32x4 acc[16];
  #pragma unroll
  for (int nt = 0; nt < 16; ++nt) {
    const bf16x8 bfr2 = *(const bf16x8*)&kb[(16 * nt + lr) * KSTR + lq * 8];
    f32x4 z = {0.f, 0.f, 0.f, 0.f};
    acc[nt] = __builtin_amdgcn_mfma_f32_16x16x32_bf16(afr, bfr2, z, 0, 0, 0);
  }

  int par[4];
  float m[4], spa[4], es[4], ts[4];
  #pragma unroll
  for (int reg = 0; reg < 4; ++reg) {
    const int r = row0 + 4 * lq + reg;
    par[reg] = (r < qlen) ? (prev_actions[qstart + r] & (ME - 1)) : -1;
    m[reg] = MASKVAL; spa[reg] = MASKVAL; es[reg] = 0.f; ts[reg] = 0.f;
  }

  #pragma unroll
  for (int nt = 0; nt < 16; ++nt) {
    const int col = 16 * nt + lr;
    const bool kv = (col < klen);
    #pragma unroll
    for (int reg = 0; reg < 4; ++reg) {
      const float d = kv ? acc[nt][reg] * QK_SCALE : MASKVAL;
      acc[nt][reg] = d;
      m[reg] = fmaxf(m[reg], d);
      if (col == par[reg]) spa[reg] = d;
    }
  }
  #pragma unroll
  for (int off = 1; off < 16; off <<= 1) {
    #pragma unroll
    for (int reg = 0; reg < 4; ++reg) {
      m[reg]   = fmaxf(m[reg],   __shfl_xor(m[reg],   off));
      spa[reg] = fmaxf(spa[reg], __shfl_xor(spa[reg], off));
    }
  }
  #pragma unroll
  for (int nt = 0; nt < 16; ++nt) {
    #pragma unroll
    for (int reg = 0; reg < 4; ++reg) {
      const float dd = acc[nt][reg] - m[reg];
      if (dd > -80.f) { const float e = __expf(dd); es[reg] += e; ts[reg] += e * dd; }
    }
  }
  #pragma unroll
  for (int off = 1; off < 16; off <<= 1) {
    #pragma unroll
    for (int reg = 0; reg < 4; ++reg) {
      es[reg] += __shfl_xor(es[reg], off);
      ts[reg] += __shfl_xor(ts[reg], off);
    }
  }

  // logits out: per instruction 16 consecutive cols x 4 rows (64B runs)
  #pragma unroll
  for (int nt = 0; nt < 16; ++nt) {
    #pragma unroll
    for (int reg = 0; reg < 4; ++reg) {
      const int r = row0 + 4 * lq + reg;
      out_lg[r * ME + 16 * nt + lr] = (r < qlen) ? acc[nt][reg] : MASKVAL;
    }
  }
  if (lr == 0) {
    #pragma unroll
    for (int reg = 0; reg < 4; ++reg) {
      const int r = row0 + 4 * lq + reg;
      if (r < qlen) {
        const float lS = __logf(fmaxf(es[reg], 1e-30f));
        out[qstart + r]         = (float)par[reg];
        out[A + qstart + r]     = spa[reg] - m[reg] - lS;
        out[2 * A + qstart + r] = lS - ts[reg] / es[reg];
      }
    }
  }
}

extern "C" void kernel_launch(void* const* d_in, const int* in_sizes, int n_in,
                              void* d_out, int out_size, void* d_ws, size_t ws_size,
                              hipStream_t stream) {
  const float* x  = (const float*)d_in[0];
  const float* Wq = (const float*)d_in[1];
  const float* bq = (const float*)d_in[2];
  const float* Wk = (const float*)d_in[3];
  const float* bk = (const float*)d_in[4];
  const int* actors       = (const int*)d_in[5];
  const int* qindices     = (const int*)d_in[6];
  const int* actees       = (const int*)d_in[7];
  const int* kindices     = (const int*)d_in[8];
  const int* prev_actions = (const int*)d_in[9];

  const int A = in_sizes[5];
  const int E = in_sizes[7];
  const int B = (out_size - 3 * A) / ENVSTRIDE;
  if (B <= 0) return;

  fused_env<<<dim3(B), dim3(256), 0, stream>>>(
      x, Wq, bq, Wk, bk, actors, qindices, actees, kindices, prev_actions,
      A, E, (float*)d_out);
}

// Round 10
// 41.064 us; speedup vs baseline: 3.4857x; 1.0052x over previous
//
#include <hip/hip_runtime.h>
#include <math.h>

#define MA 64
#define ME 256
#define DM 256
#define DQK 32
#define ENVSTRIDE (MA * ME)            // 16384 floats per env
#define MASKVAL -998244352.0f          // bf16-rounded -1e9 (matches reference)
#define QK_SCALE 0.17677669529663687f  // 1/sqrt(32)
#define KSTR 40                        // LDS row stride in ushorts (80B)

typedef __attribute__((ext_vector_type(8))) short bf16x8;
typedef __attribute__((ext_vector_type(4))) float f32x4;
typedef unsigned short u16;

__device__ __forceinline__ int lb(const int* __restrict__ a, int n, int v){
  int lo = 0, hi = n;
  while (lo < hi){ int mid = (lo + hi) >> 1; if (a[mid] < v) lo = mid + 1; else hi = mid; }
  return lo;
}
// round-to-nearest-even f32 -> bf16 (validated round 8/9)
__device__ __forceinline__ unsigned pk2bf(float lo, float hi){
  unsigned ul = __float_as_uint(lo); ul = ul + 0x7FFFu + ((ul >> 16) & 1u);
  unsigned uh = __float_as_uint(hi); uh = uh + 0x7FFFu + ((uh >> 16) & 1u);
  return (ul >> 16) | (uh & 0xFFFF0000u);
}
__device__ __forceinline__ u16 f2bu(float f){
  unsigned u = __float_as_uint(f);
  return (u16)((u + 0x7FFFu + ((u >> 16) & 1u)) >> 16);
}

__global__ __launch_bounds__(256)
void fused_env(const float* __restrict__ x,  const float* __restrict__ Wq, const float* __restrict__ bq,
               const float* __restrict__ Wk, const float* __restrict__ bk,
               const int* __restrict__ actors, const int* __restrict__ qindices,
               const int* __restrict__ actees, const int* __restrict__ kindices,
               const int* __restrict__ prev_actions, int A, int E, float* __restrict__ out)
{
  // W fragments pre-packed in MFMA order: [which][kk][nt][lane] bf16x8
  __shared__ __align__(16) unsigned wfr32[2 * 8 * 2 * 256];   // 32 KB
  __shared__ u16 kb[ME * KSTR];    // 20 KB bf16 keys
  __shared__ u16 qsm[MA * KSTR];   //  5 KB bf16 queries
  __shared__ int srange[4];

  const int t = threadIdx.x, b = blockIdx.x;
  if (t < 4) {
    const int* arr = (t < 2) ? qindices : kindices;
    const int nn = (t < 2) ? A : E;
    const int vv = (t == 0) ? b * MA : (t == 1) ? (b + 1) * MA
                 : (t == 2) ? b * ME : (b + 1) * ME;
    srange[t] = lb(arr, nn, vv);
  }

  // ---- cooperative W-fragment pack (one-time; validated layout from rounds 8/9) ----
  #pragma unroll
  for (int ii = 0; ii < 32; ++ii) {
    const int i = t + ii * 256;
    const int p = i & 3, ln = (i >> 2) & 63, nt = (i >> 8) & 1, kk = (i >> 9) & 7, wh = i >> 12;
    const int k0  = kk * 32 + (ln >> 4) * 8 + 2 * p;
    const int col = nt * 16 + (ln & 15);
    const float* W = wh ? Wq : Wk;
    wfr32[i] = pk2bf(W[(size_t)k0 * DQK + col], W[(size_t)(k0 + 1) * DQK + col]);
  }
  __syncthreads();

  const int qstart = srange[0], qlen = srange[1] - srange[0];
  const int kstart = srange[2], klen = srange[3] - srange[2];

  const int lane = t & 63, w = t >> 6;
  const int lr = lane & 15, lq = lane >> 4;

  const float bkv0 = bk[lr], bkv1 = bk[16 + lr];
  const float bqv0 = bq[lr], bqv1 = bq[16 + lr];

  // ---- projection: merged K+Q tile list, wave-strided for balance ----
  const int kt = (klen + 15) >> 4;
  const int qt = (qlen + 15) >> 4;
  const int ntiles = kt + qt;

  for (int i = w; i < ntiles; i += 4) {
    const bool isk = (i < kt);
    const int  rbase = isk ? (i << 4) : ((i - kt) << 4);
    const int  len   = isk ? klen : qlen;
    const int  start = isk ? kstart : qstart;
    const int* gath  = isk ? actees : actors;
    u16*       dst   = isk ? kb : qsm;
    const unsigned* fbase = &wfr32[(isk ? 0 : 4096) + lane * 4];

    const int arow = start + min(rbase + lr, len - 1);
    const float* xr = x + (size_t)gath[arow] * DM + lq * 8;

    float4 cx[16];
    #pragma unroll
    for (int kk = 0; kk < 8; ++kk) {
      cx[2*kk]   = *(const float4*)(xr + kk * 32);
      cx[2*kk+1] = *(const float4*)(xr + kk * 32 + 4);
    }

    const float v0 = isk ? bkv0 : bqv0, v1 = isk ? bkv1 : bqv1;
    f32x4 a0 = {v0, v0, v0, v0}, a1 = {v1, v1, v1, v1};
    #pragma unroll
    for (int kk = 0; kk < 8; ++kk) {
      union { unsigned u[4]; bf16x8 v; } fa;
      fa.u[0] = pk2bf(cx[2*kk].x,   cx[2*kk].y);
      fa.u[1] = pk2bf(cx[2*kk].z,   cx[2*kk].w);
      fa.u[2] = pk2bf(cx[2*kk+1].x, cx[2*kk+1].y);
      fa.u[3] = pk2bf(cx[2*kk+1].z, cx[2*kk+1].w);
      const bf16x8 b0 = *(const bf16x8*)(fbase + kk * 512);
      const bf16x8 b1 = *(const bf16x8*)(fbase + kk * 512 + 256);
      a0 = __builtin_amdgcn_mfma_f32_16x16x32_bf16(fa.v, b0, a0, 0, 0, 0);
      a1 = __builtin_amdgcn_mfma_f32_16x16x32_bf16(fa.v, b1, a1, 0, 0, 0);
    }
    // D: col = lane&15, row = 4*(lane>>4)+reg (validated)
    #pragma unroll
    for (int reg = 0; reg < 4; ++reg) {
      const int row = rbase + 4 * lq + reg;
      if (row < len) {
        dst[row * KSTR + lr]      = f2bu(a0[reg]);
        dst[row * KSTR + 16 + lr] = f2bu(a1[reg]);
      }
    }
  }
  __syncthreads();

  // ---- logits + softmax: wave w owns q rows 16w..16w+15 (validated round 9) ----
  float* out_lg = out + (size_t)3 * A + (size_t)b * ENVSTRIDE;
  const int row0 = 16 * w;

  if (row0 >= qlen) {          // fully padded rows: MASKVAL fill
    const float4 mv = make_float4(MASKVAL, MASKVAL, MASKVAL, MASKVAL);
    float4* o4 = (float4*)out_lg;
    #pragma unroll
    for (int rr = 0; rr < 16; ++rr) o4[(row0 + rr) * 64 + lane] = mv;
    return;
  }

  const bf16x8 afr = *(const bf16x8*)&qsm[(row0 + lr) * KSTR + lq * 8];
  f32x4 acc[16];
  #pragma unroll
  for (int nt = 0; nt < 16; ++nt) {
    const bf16x8 bfr2 = *(const bf16x8*)&kb[(16 * nt + lr) * KSTR + lq * 8];
    f32x4 z = {0.f, 0.f, 0.f, 0.f};
    acc[nt] = __builtin_amdgcn_mfma_f32_16x16x32_bf16(afr, bfr2, z, 0, 0, 0);
  }

  int par[4];
  float m[4], spa[4], es[4], ts[4];
  #pragma unroll
  for (int reg = 0; reg < 4; ++reg) {
    const int r = row0 + 4 * lq + reg;
    par[reg] = (r < qlen) ? (prev_actions[qstart + r] & (ME - 1)) : -1;
    m[reg] = MASKVAL; spa[reg] = MASKVAL; es[reg] = 0.f; ts[reg] = 0.f;
  }

  #pragma unroll
  for (int nt = 0; nt < 16; ++nt) {
    const int col = 16 * nt + lr;
    const bool kv = (col < klen);
    #pragma unroll
    for (int reg = 0; reg < 4; ++reg) {
      const float d = kv ? acc[nt][reg] * QK_SCALE : MASKVAL;
      acc[nt][reg] = d;
      m[reg] = fmaxf(m[reg], d);
      if (col == par[reg]) spa[reg] = d;
    }
  }
  #pragma unroll
  for (int off = 1; off < 16; off <<= 1) {
    #pragma unroll
    for (int reg = 0; reg < 4; ++reg) {
      m[reg]   = fmaxf(m[reg],   __shfl_xor(m[reg],   off));
      spa[reg] = fmaxf(spa[reg], __shfl_xor(spa[reg], off));
    }
  }
  #pragma unroll
  for (int nt = 0; nt < 16; ++nt) {
    #pragma unroll
    for (int reg = 0; reg < 4; ++reg) {
      const float dd = acc[nt][reg] - m[reg];
      if (dd > -80.f) { const float e = __expf(dd); es[reg] += e; ts[reg] += e * dd; }
    }
  }
  #pragma unroll
  for (int off = 1; off < 16; off <<= 1) {
    #pragma unroll
    for (int reg = 0; reg < 4; ++reg) {
      es[reg] += __shfl_xor(es[reg], off);
      ts[reg] += __shfl_xor(ts[reg], off);
    }
  }

  #pragma unroll
  for (int nt = 0; nt < 16; ++nt) {
    #pragma unroll
    for (int reg = 0; reg < 4; ++reg) {
      const int r = row0 + 4 * lq + reg;
      out_lg[r * ME + 16 * nt + lr] = (r < qlen) ? acc[nt][reg] : MASKVAL;
    }
  }
  if (lr == 0) {
    #pragma unroll
    for (int reg = 0; reg < 4; ++reg) {
      const int r = row0 + 4 * lq + reg;
      if (r < qlen) {
        const float lS = __logf(fmaxf(es[reg], 1e-30f));
        out[qstart + r]         = (float)par[reg];
        out[A + qstart + r]     = spa[reg] - m[reg] - lS;
        out[2 * A + qstart + r] = lS - ts[reg] / es[reg];
      }
    }
  }
}

extern "C" void kernel_launch(void* const* d_in, const int* in_sizes, int n_in,
                              void* d_out, int out_size, void* d_ws, size_t ws_size,
                              hipStream_t stream) {
  const float* x  = (const float*)d_in[0];
  const float* Wq = (const float*)d_in[1];
  const float* bq = (const float*)d_in[2];
  const float* Wk = (const float*)d_in[3];
  const float* bk = (const float*)d_in[4];
  const int* actors       = (const int*)d_in[5];
  const int* qindices     = (const int*)d_in[6];
  const int* actees       = (const int*)d_in[7];
  const int* kindices     = (const int*)d_in[8];
  const int* prev_actions = (const int*)d_in[9];

  const int A = in_sizes[5];
  const int E = in_sizes[7];
  const int B = (out_size - 3 * A) / ENVSTRIDE;
  if (B <= 0) return;

  fused_env<<<dim3(B), dim3(256), 0, stream>>>(
      x, Wq, bq, Wk, bk, actors, qindices, actees, kindices, prev_actions,
      A, E, (float*)d_out);
}